// Round 12
// baseline (674.448 us; speedup 1.0000x reference)
//
#include <hip/hip_runtime.h>
#include <math.h>

// ============================================================================
// RPN pipeline for MI355X.
// L0: H=W=32, stride 8, scale 4096 ; L1: H=W=16, stride 16, scale 16384
// A=3 ratios {0.5,1,2}. N0=3072, N1=768 anchors/batch. BS=4.
// Numeric recipe (validated bitwise R1-R13, absmax 0.0): fp64 accumulation for
// every sum feeding the score/box path, fp32 rounding at layer boundaries.
// R18 (best: 467.7us, conv 152us): f64 MFMA conv + on-device D-layout probe.
// R22/R23: conv occupancy & per-wave-density theories falsified; CONV FROZEN.
// R24: flat bit-serial nms 2x slower; REVERTED to ballot scan (~81us).
// R25/R26: cooperative-launch fusion -> container failed twice (graph capture
// aborts on hipLaunchCooperativeKernel; R26's 2x residency margin ruled out
// capacity deadlock). API abandoned.
// R27: same fused post-conv kernel, grid-wide sync via SOFTWARE barrier:
// plain <<<512,256>>> launch; 4 device-scope atomic counters in d_ws, zeroed
// per launch by hipMemsetAsync (stream-ordered, graph-capturable, used by the
// harness itself). Barrier: syncthreads -> t0 {fence; arrive; spin<512 with
// s_sleep; fence} -> syncthreads. Deadlock-safe by RESIDENCY (not ordering):
// 512 blocks @ 12KB LDS, <=128 VGPR, bounds(256,4) -> capacity >= 1024 blocks;
// all co-resident, no block waits on an unlaunched block (G16-compliant).
// Phase bodies byte-identical to the R18-validated standalone kernels.
// Purpose: fused dispatch dur_us measures true downstream GPU time gap-free.
// ============================================================================

typedef double d4 __attribute__((ext_vector_type(4)));

// ---------------- merged conv3x3 implicit GEMM, split-K, f64 MFMA -----------
__global__ __launch_bounds__(256, 4) void conv3_sk_u(
    const float* __restrict__ feat0, const float* __restrict__ feat1,
    const float* __restrict__ conv_w,
    double* __restrict__ part0, double* __restrict__ part1)
{
  __shared__ float Ald[2][16][72];
  __shared__ float Bld[2][16][72];
  const int t = threadIdx.x;
  const int bid = blockIdx.x;
  const float* feat;
  double* part;
  int oc_t, p_t, k_base, hw_sh, w_sh, H;
  if (bid < 1024) {
    int kc = bid >> 8;
    feat = feat0; part = part0 + (size_t)kc * 4096 * 256;
    oc_t = bid & 3; p_t = (bid >> 2) & 63;
    k_base = kc * 576; hw_sh = 10; w_sh = 5; H = 32;
  } else {
    int b2 = bid - 1024;
    int kc = b2 >> 6;
    feat = feat1; part = part1 + (size_t)kc * 1024 * 256;
    oc_t = b2 & 3; p_t = (b2 >> 2) & 15;
    k_base = kc * 576; hw_sh = 8; w_sh = 4; H = 16;
  }
  const int oc_base = oc_t * 64;
  const int p_base  = p_t * 64;
  const int wmask = H - 1, hwmask = (1 << hw_sh) - 1;
  const int skk = t >> 4;
  const int q4  = (t & 15) * 4;

  float a_r[4], b_r[4];
  auto load_tile = [&](int kt) {
    const int k0 = k_base + kt * 16;
    const float* wrow = conv_w + (size_t)(oc_base + q4) * 2304 + (k0 + skk);
#pragma unroll
    for (int u = 0; u < 4; ++u) a_r[u] = wrow[(size_t)u * 2304];
    int p = p_base + q4;
    int b = p >> hw_sh, pin = p & hwmask;
    int y = pin >> w_sh, x0 = pin & wmask;
    int k = k0 + skk;
    int ic = k / 9, rr = k - ic * 9;
    int ky = rr / 3, kx = rr - ky * 3;
    int iy = y + ky - 1;
    const float* frow = feat + (((b << 8) + ic) << hw_sh) + (iy << w_sh);
    bool yok = (unsigned)iy < (unsigned)H;
#pragma unroll
    for (int u = 0; u < 4; ++u) {
      int ix = x0 + u + kx - 1;
      b_r[u] = (yok && (unsigned)ix < (unsigned)H) ? frow[ix] : 0.f;
    }
  };

  const int lane = t & 63;
  const int wv = t >> 6;
  const int wo = (wv >> 1) << 5;
  const int wp = (wv & 1) << 5;
  const int lr = lane >> 4;
  const int lc = lane & 15;

  // -------- on-device D-layout probe (2 MFMAs, negligible cost) -----------
  int rowm[4], colm[4];
  {
    d4 pz = {0.0, 0.0, 0.0, 0.0};
    double pa1 = (lr == 0) ? (double)(lc + 1) : 0.0;
    double pb1 = (lr == 0) ? 1.0 : 0.0;
    d4 prow = __builtin_amdgcn_mfma_f64_16x16x4f64(pa1, pb1, pz, 0, 0, 0);
    double pa2 = (lr == 0) ? 1.0 : 0.0;
    double pb2 = (lr == 0) ? (double)(lc + 1) : 0.0;
    d4 pcol = __builtin_amdgcn_mfma_f64_16x16x4f64(pa2, pb2, pz, 0, 0, 0);
#pragma unroll
    for (int d = 0; d < 4; ++d) {
      rowm[d] = ((int)prow[d] - 1) & 15;
      colm[d] = ((int)pcol[d] - 1) & 15;
    }
  }

  d4 acc00 = {0.0, 0.0, 0.0, 0.0};
  d4 acc01 = {0.0, 0.0, 0.0, 0.0};
  d4 acc10 = {0.0, 0.0, 0.0, 0.0};
  d4 acc11 = {0.0, 0.0, 0.0, 0.0};

  load_tile(0);
  for (int kt = 0; kt < 36; ++kt) {
    const int buf = kt & 1;
    *(float4*)&Ald[buf][skk][q4] = make_float4(a_r[0], a_r[1], a_r[2], a_r[3]);
    *(float4*)&Bld[buf][skk][q4] = make_float4(b_r[0], b_r[1], b_r[2], b_r[3]);
    __syncthreads();
    if (kt + 1 < 36) load_tile(kt + 1);
#pragma unroll
    for (int kc = 0; kc < 4; ++kc) {
      const int kr = (kc << 2) + lr;
      double a0 = (double)Ald[buf][kr][wo + lc];
      double a1 = (double)Ald[buf][kr][wo + 16 + lc];
      double b0 = (double)Bld[buf][kr][wp + lc];
      double b1 = (double)Bld[buf][kr][wp + 16 + lc];
      acc00 = __builtin_amdgcn_mfma_f64_16x16x4f64(a0, b0, acc00, 0, 0, 0);
      acc01 = __builtin_amdgcn_mfma_f64_16x16x4f64(a0, b1, acc01, 0, 0, 0);
      acc10 = __builtin_amdgcn_mfma_f64_16x16x4f64(a1, b0, acc10, 0, 0, 0);
      acc11 = __builtin_amdgcn_mfma_f64_16x16x4f64(a1, b1, acc11, 0, 0, 0);
    }
  }

  {
    const int p00 = p_base + wp;
    const int oc00 = oc_base + wo;
#pragma unroll
    for (int d = 0; d < 4; ++d) {
      const int rm = rowm[d], cm = colm[d];
      part[(size_t)(p00 + cm)      * 256 + (oc00 + rm)]      = acc00[d];
      part[(size_t)(p00 + 16 + cm) * 256 + (oc00 + rm)]      = acc01[d];
      part[(size_t)(p00 + cm)      * 256 + (oc00 + 16 + rm)] = acc10[d];
      part[(size_t)(p00 + 16 + cm) * 256 + (oc00 + 16 + rm)] = acc11[d];
    }
  }
}

// ---- software grid barrier: residency-based (512 co-resident blocks) -------
__device__ __forceinline__ void soft_barrier(unsigned int* bar, int idx) {
  __syncthreads();
  if (threadIdx.x == 0) {
    __threadfence();                        // release prior writes
    atomicAdd(&bar[idx], 1u);
    while (atomicAdd(&bar[idx], 0u) < 512u) // device-scope atomic read
      __builtin_amdgcn_s_sleep(8);
    __threadfence();                        // acquire others' writes
  }
  __syncthreads();
}

// ======== fused post-conv pipeline: rhd -> sort -> mask -> nms -> final =====
__global__ __launch_bounds__(256, 4) void fused_post_k(
    const double* __restrict__ part0, const double* __restrict__ part1,
    const float* __restrict__ conv_b,
    const float* __restrict__ cls_w, const float* __restrict__ cls_b,
    const float* __restrict__ reg_w, const float* __restrict__ reg_b,
    float* __restrict__ box0, float* __restrict__ sc0,
    float* __restrict__ box1, float* __restrict__ sc1,
    float* __restrict__ sbox0, float* __restrict__ ssc0,
    float* __restrict__ sbox1, float* __restrict__ ssc1,
    unsigned long long* __restrict__ mask0, unsigned long long* __restrict__ mask1,
    unsigned long long* __restrict__ colD0, unsigned long long* __restrict__ colD1,
    float* __restrict__ cb, float* __restrict__ cs,
    float* __restrict__ out, unsigned int* bar)
{
  __shared__ __align__(16) char smem[12288];   // 12 KB arena, aliased per phase
  const int t = threadIdx.x;

  // ---------------- P0: reduce(KS=4)+bias+ReLU + heads + decode -------------
  for (int u = blockIdx.x; u < 1280; u += 512) {
    int wid = (u * 256 + t) >> 6;
    int lane = t & 63;
    int lvl = wid >= 4096;
    const double* part = lvl ? part1 : part0;
    int p = lvl ? wid - 4096 : wid;
    int M = lvl ? 1024 : 4096;
    double s4[4];
    {
      float4 bv = ((const float4*)conv_b)[lane];
      s4[0] = (double)bv.x; s4[1] = (double)bv.y;
      s4[2] = (double)bv.z; s4[3] = (double)bv.w;
    }
#pragma unroll
    for (int ks = 0; ks < 4; ++ks) {
      const double2* pr = (const double2*)(part + (size_t)ks * M * 256 + (size_t)p * 256);
      double2 a = pr[2 * lane], b = pr[2 * lane + 1];
      s4[0] += a.x; s4[1] += a.y; s4[2] += b.x; s4[3] += b.y;
    }
    float xv[4];
#pragma unroll
    for (int q = 0; q < 4; ++q) {
      float f = (float)s4[q];
      xv[q] = f > 0.f ? f : 0.f;
    }
    double acc[15];
#pragma unroll
    for (int o = 0; o < 15; ++o) {
      const float* wr = (o < 3) ? (cls_w + o * 256) : (reg_w + (o - 3) * 256);
      float4 wv = ((const float4*)wr)[lane];
      acc[o] = (double)wv.x * (double)xv[0] + (double)wv.y * (double)xv[1] +
               (double)wv.z * (double)xv[2] + (double)wv.w * (double)xv[3];
    }
#pragma unroll
    for (int d = 1; d < 64; d <<= 1)
#pragma unroll
      for (int o = 0; o < 15; ++o)
        acc[o] += __shfl_xor(acc[o], d, 64);
    if (lane < 3) {
      int a = lane;
      float cls = (float)(acc[a] + (double)cls_b[a]);
      float score = 1.f / (1.f + expf(-cls));
      float dx = (float)(acc[3 + a * 4 + 0] + (double)reg_b[a * 4 + 0]);
      float dy = (float)(acc[3 + a * 4 + 1] + (double)reg_b[a * 4 + 1]);
      float dw = (float)(acc[3 + a * 4 + 2] + (double)reg_b[a * 4 + 2]);
      float dh = (float)(acc[3 + a * 4 + 3] + (double)reg_b[a * 4 + 3]);
      int hw_sh = lvl ? 8 : 10, w_sh = lvl ? 4 : 5, Wd = lvl ? 16 : 32;
      float S = lvl ? 16.f : 8.f;
      double scale = lvl ? 16384.0 : 4096.0;
      int b = p >> hw_sh, pin = p & ((1 << hw_sh) - 1);
      int y = pin >> w_sh, x = pin & (Wd - 1);
      double ratio = (a == 0) ? 0.5 : (a == 1 ? 1.0 : 2.0);
      float w_a = (float)sqrt(scale / ratio);
      float h_a = (float)sqrt(scale * ratio);
      float cx = ((float)x + 0.5f) * S;
      float cy = ((float)y + 0.5f) * S;
      float x1 = cx - 0.5f * w_a, y1 = cy - 0.5f * h_a;
      float x2 = cx + 0.5f * w_a, y2 = cy + 0.5f * h_a;
      x1 = fminf(fmaxf(x1, 0.f), 256.f); y1 = fminf(fmaxf(y1, 0.f), 256.f);
      x2 = fminf(fmaxf(x2, 0.f), 256.f); y2 = fminf(fmaxf(y2, 0.f), 256.f);
      float wa = x2 - x1, ha = y2 - y1;
      float cxa = x1 + 0.5f * wa, cya = y1 + 0.5f * ha;
      float ncx = dx * wa + cxa;
      float ncy = dy * ha + cya;
      float nw = expf(dw) * wa;
      float nh = expf(dh) * ha;
      float bx1 = ncx - 0.5f * nw, by1 = ncy - 0.5f * nh;
      float bx2 = ncx + 0.5f * nw, by2 = ncy + 0.5f * nh;
      bx1 = fminf(fmaxf(bx1, 0.f), 256.f); by1 = fminf(fmaxf(by1, 0.f), 256.f);
      bx2 = fminf(fmaxf(bx2, 0.f), 256.f); by2 = fminf(fmaxf(by2, 0.f), 256.f);
      int n = pin * 3 + a;
      if (lvl) {
        ((float4*)box1)[(size_t)b * 768 + n] = make_float4(bx1, by1, bx2, by2);
        sc1[b * 768 + n] = score;
      } else {
        ((float4*)box0)[(size_t)b * 3072 + n] = make_float4(bx1, by1, bx2, by2);
        sc0[b * 3072 + n] = score;
      }
    }
  }
  soft_barrier(bar, 0);

  // ---------------- P1: stable descending enumeration sort -----------------
  if (blockIdx.x < 60) {
    float* s = (float*)smem;
    int z = blockIdx.x;
    const float *sc, *box; float *ssc, *sbox; int N, b, c;
    if (z < 48) { sc = sc0; box = box0; ssc = ssc0; sbox = sbox0; N = 3072; b = z / 12; c = z % 12; }
    else { int z2 = z - 48; sc = sc1; box = box1; ssc = ssc1; sbox = sbox1; N = 768; b = z2 / 3; c = z2 % 3; }
    const float* scb = sc + (size_t)b * N;
    for (int j = t; j < N; j += 256) s[j] = scb[j];
    __syncthreads();
    int i = c * 256 + t;
    float si = s[i];
    int rank = 0;
    const float4* sv = (const float4*)s;
    for (int j4 = 0; j4 < (N >> 2); ++j4) {
      float4 v = sv[j4];
      int j = j4 * 4;
      rank += (v.x > si) || (v.x == si && (j + 0) < i);
      rank += (v.y > si) || (v.y == si && (j + 1) < i);
      rank += (v.z > si) || (v.z == si && (j + 2) < i);
      rank += (v.w > si) || (v.w == si && (j + 3) < i);
    }
    ssc[(size_t)b * N + rank] = si;
    float4 bi = ((const float4*)box)[(size_t)b * N + i];
    ((float4*)sbox)[(size_t)b * N + rank] = bi;
  }
  soft_barrier(bar, 1);

  // ---------------- P2: NMS bitmask + transposed diagonal tiles -------------
  for (int bid = blockIdx.x; bid < 2508; bid += 512) {
    if (bid < 2448) {
      float4* bj = (float4*)smem;
      const float* sbox; unsigned long long* mask; int N, words, w, i_ch, b;
      if (bid < 2304) {
        sbox = sbox0; mask = mask0; N = 3072; words = 48;
        w = bid % 48; int r = bid / 48; i_ch = r % 12; b = r / 12;
      } else {
        int z = bid - 2304;
        sbox = sbox1; mask = mask1; N = 768; words = 12;
        w = z % 12; int r = z / 12; i_ch = r % 3; b = r / 3;
      }
      int i = i_ch * 256 + t;
      if (t < 64)
        bj[t] = ((const float4*)sbox)[(size_t)b * N + w * 64 + t];
      __syncthreads();
      float4 bi = ((const float4*)sbox)[(size_t)b * N + i];
      float ai = (bi.z - bi.x) * (bi.w - bi.y);
      unsigned long long m = 0ull;
#pragma unroll 16
      for (int jj = 0; jj < 64; ++jj) {
        int j = w * 64 + jj;
        float4 bv = bj[jj];
        float lx = fmaxf(bi.x, bv.x), ly = fmaxf(bi.y, bv.y);
        float rx = fminf(bi.z, bv.z), ry = fminf(bi.w, bv.w);
        float iw = fmaxf(rx - lx, 0.f), ih = fmaxf(ry - ly, 0.f);
        float inter = iw * ih;
        float aj = (bv.z - bv.x) * (bv.w - bv.y);
        float iou = inter / (ai + aj - inter);   // NaN compares false
        if ((iou > 0.7f) & (j > i)) m |= (1ull << jj);
      }
      mask[((size_t)b * N + i) * words + w] = m;
    } else {
      float4 (*tb)[64] = (float4(*)[64])smem;
      int sub = t >> 6, lane = t & 63;
      const float* sbox; unsigned long long* colD; int N, tile, b;
      if (bid < 2496) {
        int unit = (bid - 2448) * 4 + sub;
        sbox = sbox0; colD = colD0; N = 3072;
        tile = unit % 48; b = unit / 48;
      } else {
        int unit = (bid - 2496) * 4 + sub;
        sbox = sbox1; colD = colD1; N = 768;
        tile = unit % 12; b = unit / 12;
      }
      tb[sub][lane] = ((const float4*)sbox)[(size_t)b * N + tile * 64 + lane];
      __syncthreads();
      float4 bq = tb[sub][lane];
      float aq = (bq.z - bq.x) * (bq.w - bq.y);
      unsigned long long col = 0ull;
#pragma unroll 16
      for (int ii = 0; ii < 64; ++ii) {
        float4 bi = tb[sub][ii];
        float lx = fmaxf(bq.x, bi.x), ly = fmaxf(bq.y, bi.y);
        float rx = fminf(bq.z, bi.z), ry = fminf(bq.w, bi.w);
        float iw = fmaxf(rx - lx, 0.f), ih = fmaxf(ry - ly, 0.f);
        float inter = iw * ih;
        float ai = (bi.z - bi.x) * (bi.w - bi.y);
        float iou = inter / (aq + ai - inter);
        if ((iou > 0.7f) & (lane > ii)) col |= (1ull << ii);
      }
      colD[(size_t)b * N + tile * 64 + lane] = col;
    }
    __syncthreads();   // arena reuse across unit iterations
  }
  soft_barrier(bar, 2);

  // ------ P3: exact greedy scan (R18 ballot version), blocks 0..7 -----------
  if (blockIdx.x < 8) {
    int z = blockIdx.x;
    int lvl = z >> 2, b = z & 3;
    int N = lvl ? 768 : 3072;
    int words = lvl ? 12 : 48;
    const float* ssc = (lvl ? ssc1 : ssc0) + (size_t)b * N;
    const float4* sbox = ((const float4*)(lvl ? sbox1 : sbox0)) + (size_t)b * N;
    const unsigned long long* mask = (lvl ? mask1 : mask0) + (size_t)b * N * words;
    const unsigned long long* colD = (lvl ? colD1 : colD0) + (size_t)b * N;
    const int lane = t & 63;
    const int wv = t >> 6;
    float* csb = cs + (size_t)b * 2000 + lvl * 1000;
    float4* cbb = (float4*)(cb + ((size_t)b * 2000 + lvl * 1000) * 4);

    unsigned long long* rem = (unsigned long long*)smem;                 // 384 B
    unsigned long long (*npart)[64] =
        (unsigned long long(*)[64])(smem + 384);                         // 2 KB
    unsigned long long* keepShp = (unsigned long long*)(smem + 384 + 2048);
    int* doneShp = (int*)(smem + 384 + 2048 + 8);

    if (t < 48) rem[t] = 0ull;
    if (t == 0) *doneShp = 0;
    for (int q = t; q < 1000; q += 256) {
      csb[q] = -1.f;
      cbb[q] = make_float4(-1.f, -1.f, -1.f, -1.f);
    }
    unsigned long long colv = 0ull; float sc_i = 0.f; float4 bx_i;
    if (wv == 0) { colv = colD[lane]; sc_i = ssc[lane]; bx_i = sbox[lane]; }
    int kept_base = 0;
    __syncthreads();

    for (int tt = 0; tt < words; ++tt) {
      unsigned long long v[16];
      if (lane < words) {
        const unsigned long long* rowb =
            mask + ((size_t)tt * 64 + wv * 16) * words + lane;
#pragma unroll
        for (int s = 0; s < 16; ++s) v[s] = rowb[(size_t)s * words];
      }
      if (wv == 0) {
        unsigned long long wr = rem[tt];
        bool rm = (wr >> lane) & 1ull;
        bool kp = false;
        unsigned long long Rv = wr;
        unsigned long long Kv = 0ull;
        while (true) {
          bool F = (!rm) && (!kp) && ((colv & ~Rv) == 0ull);
          unsigned long long Fv = __ballot(F);
          if (Fv == 0ull) break;
          kp = kp || F;
          Kv |= Fv;
          bool newr = (!rm) && (!kp) && ((colv & Fv) != 0ull);
          rm = rm || newr;
          Rv = __ballot(rm);
        }
        if (kp) {
          int rank = kept_base + __popcll(Kv & ((1ull << lane) - 1ull));
          if (rank < 1000) { csb[rank] = sc_i; cbb[rank] = bx_i; }
        }
        kept_base += __popcll(Kv);
        if (lane == 0) {
          *keepShp = Kv;
          *doneShp = (kept_base >= 1000 || tt + 1 >= words) ? 1 : 0;
        }
        if (tt + 1 < words) {
          int i2 = (tt + 1) * 64 + lane;
          colv = colD[i2]; sc_i = ssc[i2]; bx_i = sbox[i2];
        }
      }
      __syncthreads();
      unsigned long long k64 = *keepShp;
      int done = *doneShp;
      if (lane < words) {
        unsigned long long acc = 0ull;
#pragma unroll
        for (int s = 0; s < 16; ++s)
          acc |= (((k64 >> (wv * 16 + s)) & 1ull) ? v[s] : 0ull);
        npart[wv][lane] = acc;
      }
      __syncthreads();
      if (done) break;
      if (t > tt && t < words)
        rem[t] |= npart[0][t] | npart[1][t] | npart[2][t] | npart[3][t];
      __syncthreads();
    }
  }
  soft_barrier(bar, 3);

  // ------ P4: final stable descending sort of 2000, gather boxes ------------
  if (blockIdx.x < 32) {
    float* s = (float*)smem;
    int b = blockIdx.x >> 3, c = blockIdx.x & 7;
    const float* csb = cs + (size_t)b * 2000;
    for (int j = t; j < 2000; j += 256) s[j] = csb[j];
    __syncthreads();
    if (t < 250) {
      int li = c * 250 + t;
      float si = s[li];
      int rank = 0;
      const float4* sv = (const float4*)s;
      for (int j4 = 0; j4 < 500; ++j4) {
        float4 v = sv[j4];
        int j = j4 * 4;
        rank += (v.x > si) || (v.x == si && (j + 0) < li);
        rank += (v.y > si) || (v.y == si && (j + 1) < li);
        rank += (v.z > si) || (v.z == si && (j + 2) < li);
        rank += (v.w > si) || (v.w == si && (j + 3) < li);
      }
      float4 bi = ((const float4*)cb)[(size_t)b * 2000 + li];
      ((float4*)out)[(size_t)b * 2000 + rank] = bi;
    }
  }
}

// ============================================================================
extern "C" void kernel_launch(void* const* d_in, const int* in_sizes, int n_in,
                              void* d_out, int out_size, void* d_ws, size_t ws_size,
                              hipStream_t stream) {
  const float* feat0  = (const float*)d_in[0];
  const float* feat1  = (const float*)d_in[1];
  const float* conv_w = (const float*)d_in[2];
  const float* conv_b = (const float*)d_in[3];
  const float* cls_w  = (const float*)d_in[4];
  const float* cls_b  = (const float*)d_in[5];
  const float* reg_w  = (const float*)d_in[6];
  const float* reg_b  = (const float*)d_in[7];

  char* p = (char*)d_ws;
  auto alloc = [&](size_t bytes) {
    char* r = p;
    p += (bytes + 255) & ~(size_t)255;
    return r;
  };
  double* part0 = (double*)alloc((size_t)4 * 4096 * 256 * 8);    // 33.6 MB
  double* part1 = (double*)alloc((size_t)4 * 1024 * 256 * 8);    //  8.4 MB
  float* box0 = (float*)alloc((size_t)4 * 3072 * 16);
  float* sc0  = (float*)alloc((size_t)4 * 3072 * 4);
  float* box1 = (float*)alloc((size_t)4 * 768 * 16);
  float* sc1  = (float*)alloc((size_t)4 * 768 * 4);
  float* sbox0 = (float*)alloc((size_t)4 * 3072 * 16);
  float* ssc0  = (float*)alloc((size_t)4 * 3072 * 4);
  float* sbox1 = (float*)alloc((size_t)4 * 768 * 16);
  float* ssc1  = (float*)alloc((size_t)4 * 768 * 4);
  unsigned long long* mask0 = (unsigned long long*)alloc((size_t)4 * 3072 * 48 * 8);
  unsigned long long* mask1 = (unsigned long long*)alloc((size_t)4 * 768 * 12 * 8);
  unsigned long long* colD0 = (unsigned long long*)alloc((size_t)4 * 3072 * 8);
  unsigned long long* colD1 = (unsigned long long*)alloc((size_t)4 * 768 * 8);
  float* cb = (float*)alloc((size_t)4 * 2000 * 16);
  float* cs = (float*)alloc((size_t)4 * 2000 * 4);
  unsigned int* bar = (unsigned int*)alloc(256);
  float* outp = (float*)d_out;

  hipMemsetAsync(bar, 0, 256, stream);   // zero barrier counters (per launch)
  conv3_sk_u<<<1280, 256, 0, stream>>>(feat0, feat1, conv_w, part0, part1);
  fused_post_k<<<512, 256, 0, stream>>>(
      part0, part1, conv_b, cls_w, cls_b, reg_w, reg_b,
      box0, sc0, box1, sc1, sbox0, ssc0, sbox1, ssc1,
      mask0, mask1, colD0, colD1, cb, cs, outp, bar);
}

// Round 13
// 668.327 us; speedup vs baseline: 1.0092x; 1.0092x over previous
//
#include <hip/hip_runtime.h>
#include <math.h>

// ============================================================================
// RPN pipeline for MI355X.
// L0: H=W=32, stride 8, scale 4096 ; L1: H=W=16, stride 16, scale 16384
// A=3 ratios {0.5,1,2}. N0=3072, N1=768 anchors/batch. BS=4.
// Numeric recipe (validated bitwise R1-R13, absmax 0.0): fp64 accumulation for
// every sum feeding the score/box path, fp32 rounding at layer boundaries.
// R18 (best 6-kernel: 467.7us, conv 152us): f64 MFMA conv + D-layout probe.
// R22/R23: conv occupancy & density theories falsified; CONV FROZEN (152us).
// R24: flat bit-serial nms 2x slower; ballot scan restored (~81us).
// R25/R26: hipLaunchCooperativeKernel aborts harness graph capture. Abandoned.
// R27 (passed, 674us): software-barrier fused post-conv kernel CORRECT
// (absmax 0.0) but fused dur 480us. Smoking gun: WRITE_SIZE 65MB vs ~8MB of
// real writes = ~1M cacheline writebacks from the atomicAdd(+0) POLL — on
// MI355X device-scope RMWs resolve at the cross-XCD coherence point (write
// through toward L3/HBM), serializing exclusive ownership of one line.
// R28: poll with __hip_atomic_load (RELAXED, AGENT scope) — device-coherent
// LOAD, no ownership, concurrent polls served in parallel — + s_sleep(32)
// (4x fewer polls). Arrival atomicAdd + fences unchanged (validated R27).
// Everything else byte-identical to R27.
// ============================================================================

typedef double d4 __attribute__((ext_vector_type(4)));

// ---------------- merged conv3x3 implicit GEMM, split-K, f64 MFMA -----------
__global__ __launch_bounds__(256, 4) void conv3_sk_u(
    const float* __restrict__ feat0, const float* __restrict__ feat1,
    const float* __restrict__ conv_w,
    double* __restrict__ part0, double* __restrict__ part1)
{
  __shared__ float Ald[2][16][72];
  __shared__ float Bld[2][16][72];
  const int t = threadIdx.x;
  const int bid = blockIdx.x;
  const float* feat;
  double* part;
  int oc_t, p_t, k_base, hw_sh, w_sh, H;
  if (bid < 1024) {
    int kc = bid >> 8;
    feat = feat0; part = part0 + (size_t)kc * 4096 * 256;
    oc_t = bid & 3; p_t = (bid >> 2) & 63;
    k_base = kc * 576; hw_sh = 10; w_sh = 5; H = 32;
  } else {
    int b2 = bid - 1024;
    int kc = b2 >> 6;
    feat = feat1; part = part1 + (size_t)kc * 1024 * 256;
    oc_t = b2 & 3; p_t = (b2 >> 2) & 15;
    k_base = kc * 576; hw_sh = 8; w_sh = 4; H = 16;
  }
  const int oc_base = oc_t * 64;
  const int p_base  = p_t * 64;
  const int wmask = H - 1, hwmask = (1 << hw_sh) - 1;
  const int skk = t >> 4;
  const int q4  = (t & 15) * 4;

  float a_r[4], b_r[4];
  auto load_tile = [&](int kt) {
    const int k0 = k_base + kt * 16;
    const float* wrow = conv_w + (size_t)(oc_base + q4) * 2304 + (k0 + skk);
#pragma unroll
    for (int u = 0; u < 4; ++u) a_r[u] = wrow[(size_t)u * 2304];
    int p = p_base + q4;
    int b = p >> hw_sh, pin = p & hwmask;
    int y = pin >> w_sh, x0 = pin & wmask;
    int k = k0 + skk;
    int ic = k / 9, rr = k - ic * 9;
    int ky = rr / 3, kx = rr - ky * 3;
    int iy = y + ky - 1;
    const float* frow = feat + (((b << 8) + ic) << hw_sh) + (iy << w_sh);
    bool yok = (unsigned)iy < (unsigned)H;
#pragma unroll
    for (int u = 0; u < 4; ++u) {
      int ix = x0 + u + kx - 1;
      b_r[u] = (yok && (unsigned)ix < (unsigned)H) ? frow[ix] : 0.f;
    }
  };

  const int lane = t & 63;
  const int wv = t >> 6;
  const int wo = (wv >> 1) << 5;
  const int wp = (wv & 1) << 5;
  const int lr = lane >> 4;
  const int lc = lane & 15;

  // -------- on-device D-layout probe (2 MFMAs, negligible cost) -----------
  int rowm[4], colm[4];
  {
    d4 pz = {0.0, 0.0, 0.0, 0.0};
    double pa1 = (lr == 0) ? (double)(lc + 1) : 0.0;
    double pb1 = (lr == 0) ? 1.0 : 0.0;
    d4 prow = __builtin_amdgcn_mfma_f64_16x16x4f64(pa1, pb1, pz, 0, 0, 0);
    double pa2 = (lr == 0) ? 1.0 : 0.0;
    double pb2 = (lr == 0) ? (double)(lc + 1) : 0.0;
    d4 pcol = __builtin_amdgcn_mfma_f64_16x16x4f64(pa2, pb2, pz, 0, 0, 0);
#pragma unroll
    for (int d = 0; d < 4; ++d) {
      rowm[d] = ((int)prow[d] - 1) & 15;
      colm[d] = ((int)pcol[d] - 1) & 15;
    }
  }

  d4 acc00 = {0.0, 0.0, 0.0, 0.0};
  d4 acc01 = {0.0, 0.0, 0.0, 0.0};
  d4 acc10 = {0.0, 0.0, 0.0, 0.0};
  d4 acc11 = {0.0, 0.0, 0.0, 0.0};

  load_tile(0);
  for (int kt = 0; kt < 36; ++kt) {
    const int buf = kt & 1;
    *(float4*)&Ald[buf][skk][q4] = make_float4(a_r[0], a_r[1], a_r[2], a_r[3]);
    *(float4*)&Bld[buf][skk][q4] = make_float4(b_r[0], b_r[1], b_r[2], b_r[3]);
    __syncthreads();
    if (kt + 1 < 36) load_tile(kt + 1);
#pragma unroll
    for (int kc = 0; kc < 4; ++kc) {
      const int kr = (kc << 2) + lr;
      double a0 = (double)Ald[buf][kr][wo + lc];
      double a1 = (double)Ald[buf][kr][wo + 16 + lc];
      double b0 = (double)Bld[buf][kr][wp + lc];
      double b1 = (double)Bld[buf][kr][wp + 16 + lc];
      acc00 = __builtin_amdgcn_mfma_f64_16x16x4f64(a0, b0, acc00, 0, 0, 0);
      acc01 = __builtin_amdgcn_mfma_f64_16x16x4f64(a0, b1, acc01, 0, 0, 0);
      acc10 = __builtin_amdgcn_mfma_f64_16x16x4f64(a1, b0, acc10, 0, 0, 0);
      acc11 = __builtin_amdgcn_mfma_f64_16x16x4f64(a1, b1, acc11, 0, 0, 0);
    }
  }

  {
    const int p00 = p_base + wp;
    const int oc00 = oc_base + wo;
#pragma unroll
    for (int d = 0; d < 4; ++d) {
      const int rm = rowm[d], cm = colm[d];
      part[(size_t)(p00 + cm)      * 256 + (oc00 + rm)]      = acc00[d];
      part[(size_t)(p00 + 16 + cm) * 256 + (oc00 + rm)]      = acc01[d];
      part[(size_t)(p00 + cm)      * 256 + (oc00 + 16 + rm)] = acc10[d];
      part[(size_t)(p00 + 16 + cm) * 256 + (oc00 + 16 + rm)] = acc11[d];
    }
  }
}

// ---- software grid barrier: RMW arrive, coherent-LOAD poll (R28 fix) -------
__device__ __forceinline__ void soft_barrier(unsigned int* bar, int idx) {
  __syncthreads();
  if (threadIdx.x == 0) {
    __threadfence();                        // release prior writes
    atomicAdd(&bar[idx], 1u);
    while (__hip_atomic_load(&bar[idx], __ATOMIC_RELAXED,
                             __HIP_MEMORY_SCOPE_AGENT) < 512u)
      __builtin_amdgcn_s_sleep(32);
    __threadfence();                        // acquire others' writes
  }
  __syncthreads();
}

// ======== fused post-conv pipeline: rhd -> sort -> mask -> nms -> final =====
__global__ __launch_bounds__(256, 4) void fused_post_k(
    const double* __restrict__ part0, const double* __restrict__ part1,
    const float* __restrict__ conv_b,
    const float* __restrict__ cls_w, const float* __restrict__ cls_b,
    const float* __restrict__ reg_w, const float* __restrict__ reg_b,
    float* __restrict__ box0, float* __restrict__ sc0,
    float* __restrict__ box1, float* __restrict__ sc1,
    float* __restrict__ sbox0, float* __restrict__ ssc0,
    float* __restrict__ sbox1, float* __restrict__ ssc1,
    unsigned long long* __restrict__ mask0, unsigned long long* __restrict__ mask1,
    unsigned long long* __restrict__ colD0, unsigned long long* __restrict__ colD1,
    float* __restrict__ cb, float* __restrict__ cs,
    float* __restrict__ out, unsigned int* bar)
{
  __shared__ __align__(16) char smem[12288];   // 12 KB arena, aliased per phase
  const int t = threadIdx.x;

  // ---------------- P0: reduce(KS=4)+bias+ReLU + heads + decode -------------
  for (int u = blockIdx.x; u < 1280; u += 512) {
    int wid = (u * 256 + t) >> 6;
    int lane = t & 63;
    int lvl = wid >= 4096;
    const double* part = lvl ? part1 : part0;
    int p = lvl ? wid - 4096 : wid;
    int M = lvl ? 1024 : 4096;
    double s4[4];
    {
      float4 bv = ((const float4*)conv_b)[lane];
      s4[0] = (double)bv.x; s4[1] = (double)bv.y;
      s4[2] = (double)bv.z; s4[3] = (double)bv.w;
    }
#pragma unroll
    for (int ks = 0; ks < 4; ++ks) {
      const double2* pr = (const double2*)(part + (size_t)ks * M * 256 + (size_t)p * 256);
      double2 a = pr[2 * lane], b = pr[2 * lane + 1];
      s4[0] += a.x; s4[1] += a.y; s4[2] += b.x; s4[3] += b.y;
    }
    float xv[4];
#pragma unroll
    for (int q = 0; q < 4; ++q) {
      float f = (float)s4[q];
      xv[q] = f > 0.f ? f : 0.f;
    }
    double acc[15];
#pragma unroll
    for (int o = 0; o < 15; ++o) {
      const float* wr = (o < 3) ? (cls_w + o * 256) : (reg_w + (o - 3) * 256);
      float4 wv = ((const float4*)wr)[lane];
      acc[o] = (double)wv.x * (double)xv[0] + (double)wv.y * (double)xv[1] +
               (double)wv.z * (double)xv[2] + (double)wv.w * (double)xv[3];
    }
#pragma unroll
    for (int d = 1; d < 64; d <<= 1)
#pragma unroll
      for (int o = 0; o < 15; ++o)
        acc[o] += __shfl_xor(acc[o], d, 64);
    if (lane < 3) {
      int a = lane;
      float cls = (float)(acc[a] + (double)cls_b[a]);
      float score = 1.f / (1.f + expf(-cls));
      float dx = (float)(acc[3 + a * 4 + 0] + (double)reg_b[a * 4 + 0]);
      float dy = (float)(acc[3 + a * 4 + 1] + (double)reg_b[a * 4 + 1]);
      float dw = (float)(acc[3 + a * 4 + 2] + (double)reg_b[a * 4 + 2]);
      float dh = (float)(acc[3 + a * 4 + 3] + (double)reg_b[a * 4 + 3]);
      int hw_sh = lvl ? 8 : 10, w_sh = lvl ? 4 : 5, Wd = lvl ? 16 : 32;
      float S = lvl ? 16.f : 8.f;
      double scale = lvl ? 16384.0 : 4096.0;
      int b = p >> hw_sh, pin = p & ((1 << hw_sh) - 1);
      int y = pin >> w_sh, x = pin & (Wd - 1);
      double ratio = (a == 0) ? 0.5 : (a == 1 ? 1.0 : 2.0);
      float w_a = (float)sqrt(scale / ratio);
      float h_a = (float)sqrt(scale * ratio);
      float cx = ((float)x + 0.5f) * S;
      float cy = ((float)y + 0.5f) * S;
      float x1 = cx - 0.5f * w_a, y1 = cy - 0.5f * h_a;
      float x2 = cx + 0.5f * w_a, y2 = cy + 0.5f * h_a;
      x1 = fminf(fmaxf(x1, 0.f), 256.f); y1 = fminf(fmaxf(y1, 0.f), 256.f);
      x2 = fminf(fmaxf(x2, 0.f), 256.f); y2 = fminf(fmaxf(y2, 0.f), 256.f);
      float wa = x2 - x1, ha = y2 - y1;
      float cxa = x1 + 0.5f * wa, cya = y1 + 0.5f * ha;
      float ncx = dx * wa + cxa;
      float ncy = dy * ha + cya;
      float nw = expf(dw) * wa;
      float nh = expf(dh) * ha;
      float bx1 = ncx - 0.5f * nw, by1 = ncy - 0.5f * nh;
      float bx2 = ncx + 0.5f * nw, by2 = ncy + 0.5f * nh;
      bx1 = fminf(fmaxf(bx1, 0.f), 256.f); by1 = fminf(fmaxf(by1, 0.f), 256.f);
      bx2 = fminf(fmaxf(bx2, 0.f), 256.f); by2 = fminf(fmaxf(by2, 0.f), 256.f);
      int n = pin * 3 + a;
      if (lvl) {
        ((float4*)box1)[(size_t)b * 768 + n] = make_float4(bx1, by1, bx2, by2);
        sc1[b * 768 + n] = score;
      } else {
        ((float4*)box0)[(size_t)b * 3072 + n] = make_float4(bx1, by1, bx2, by2);
        sc0[b * 3072 + n] = score;
      }
    }
  }
  soft_barrier(bar, 0);

  // ---------------- P1: stable descending enumeration sort -----------------
  if (blockIdx.x < 60) {
    float* s = (float*)smem;
    int z = blockIdx.x;
    const float *sc, *box; float *ssc, *sbox; int N, b, c;
    if (z < 48) { sc = sc0; box = box0; ssc = ssc0; sbox = sbox0; N = 3072; b = z / 12; c = z % 12; }
    else { int z2 = z - 48; sc = sc1; box = box1; ssc = ssc1; sbox = sbox1; N = 768; b = z2 / 3; c = z2 % 3; }
    const float* scb = sc + (size_t)b * N;
    for (int j = t; j < N; j += 256) s[j] = scb[j];
    __syncthreads();
    int i = c * 256 + t;
    float si = s[i];
    int rank = 0;
    const float4* sv = (const float4*)s;
    for (int j4 = 0; j4 < (N >> 2); ++j4) {
      float4 v = sv[j4];
      int j = j4 * 4;
      rank += (v.x > si) || (v.x == si && (j + 0) < i);
      rank += (v.y > si) || (v.y == si && (j + 1) < i);
      rank += (v.z > si) || (v.z == si && (j + 2) < i);
      rank += (v.w > si) || (v.w == si && (j + 3) < i);
    }
    ssc[(size_t)b * N + rank] = si;
    float4 bi = ((const float4*)box)[(size_t)b * N + i];
    ((float4*)sbox)[(size_t)b * N + rank] = bi;
  }
  soft_barrier(bar, 1);

  // ---------------- P2: NMS bitmask + transposed diagonal tiles -------------
  for (int bid = blockIdx.x; bid < 2508; bid += 512) {
    if (bid < 2448) {
      float4* bj = (float4*)smem;
      const float* sbox; unsigned long long* mask; int N, words, w, i_ch, b;
      if (bid < 2304) {
        sbox = sbox0; mask = mask0; N = 3072; words = 48;
        w = bid % 48; int r = bid / 48; i_ch = r % 12; b = r / 12;
      } else {
        int z = bid - 2304;
        sbox = sbox1; mask = mask1; N = 768; words = 12;
        w = z % 12; int r = z / 12; i_ch = r % 3; b = r / 3;
      }
      int i = i_ch * 256 + t;
      if (t < 64)
        bj[t] = ((const float4*)sbox)[(size_t)b * N + w * 64 + t];
      __syncthreads();
      float4 bi = ((const float4*)sbox)[(size_t)b * N + i];
      float ai = (bi.z - bi.x) * (bi.w - bi.y);
      unsigned long long m = 0ull;
#pragma unroll 16
      for (int jj = 0; jj < 64; ++jj) {
        int j = w * 64 + jj;
        float4 bv = bj[jj];
        float lx = fmaxf(bi.x, bv.x), ly = fmaxf(bi.y, bv.y);
        float rx = fminf(bi.z, bv.z), ry = fminf(bi.w, bv.w);
        float iw = fmaxf(rx - lx, 0.f), ih = fmaxf(ry - ly, 0.f);
        float inter = iw * ih;
        float aj = (bv.z - bv.x) * (bv.w - bv.y);
        float iou = inter / (ai + aj - inter);   // NaN compares false
        if ((iou > 0.7f) & (j > i)) m |= (1ull << jj);
      }
      mask[((size_t)b * N + i) * words + w] = m;
    } else {
      float4 (*tb)[64] = (float4(*)[64])smem;
      int sub = t >> 6, lane = t & 63;
      const float* sbox; unsigned long long* colD; int N, tile, b;
      if (bid < 2496) {
        int unit = (bid - 2448) * 4 + sub;
        sbox = sbox0; colD = colD0; N = 3072;
        tile = unit % 48; b = unit / 48;
      } else {
        int unit = (bid - 2496) * 4 + sub;
        sbox = sbox1; colD = colD1; N = 768;
        tile = unit % 12; b = unit / 12;
      }
      tb[sub][lane] = ((const float4*)sbox)[(size_t)b * N + tile * 64 + lane];
      __syncthreads();
      float4 bq = tb[sub][lane];
      float aq = (bq.z - bq.x) * (bq.w - bq.y);
      unsigned long long col = 0ull;
#pragma unroll 16
      for (int ii = 0; ii < 64; ++ii) {
        float4 bi = tb[sub][ii];
        float lx = fmaxf(bq.x, bi.x), ly = fmaxf(bq.y, bi.y);
        float rx = fminf(bq.z, bi.z), ry = fminf(bq.w, bi.w);
        float iw = fmaxf(rx - lx, 0.f), ih = fmaxf(ry - ly, 0.f);
        float inter = iw * ih;
        float ai = (bi.z - bi.x) * (bi.w - bi.y);
        float iou = inter / (aq + ai - inter);
        if ((iou > 0.7f) & (lane > ii)) col |= (1ull << ii);
      }
      colD[(size_t)b * N + tile * 64 + lane] = col;
    }
    __syncthreads();   // arena reuse across unit iterations
  }
  soft_barrier(bar, 2);

  // ------ P3: exact greedy scan (R18 ballot version), blocks 0..7 -----------
  if (blockIdx.x < 8) {
    int z = blockIdx.x;
    int lvl = z >> 2, b = z & 3;
    int N = lvl ? 768 : 3072;
    int words = lvl ? 12 : 48;
    const float* ssc = (lvl ? ssc1 : ssc0) + (size_t)b * N;
    const float4* sbox = ((const float4*)(lvl ? sbox1 : sbox0)) + (size_t)b * N;
    const unsigned long long* mask = (lvl ? mask1 : mask0) + (size_t)b * N * words;
    const unsigned long long* colD = (lvl ? colD1 : colD0) + (size_t)b * N;
    const int lane = t & 63;
    const int wv = t >> 6;
    float* csb = cs + (size_t)b * 2000 + lvl * 1000;
    float4* cbb = (float4*)(cb + ((size_t)b * 2000 + lvl * 1000) * 4);

    unsigned long long* rem = (unsigned long long*)smem;                 // 384 B
    unsigned long long (*npart)[64] =
        (unsigned long long(*)[64])(smem + 384);                         // 2 KB
    unsigned long long* keepShp = (unsigned long long*)(smem + 384 + 2048);
    int* doneShp = (int*)(smem + 384 + 2048 + 8);

    if (t < 48) rem[t] = 0ull;
    if (t == 0) *doneShp = 0;
    for (int q = t; q < 1000; q += 256) {
      csb[q] = -1.f;
      cbb[q] = make_float4(-1.f, -1.f, -1.f, -1.f);
    }
    unsigned long long colv = 0ull; float sc_i = 0.f; float4 bx_i;
    if (wv == 0) { colv = colD[lane]; sc_i = ssc[lane]; bx_i = sbox[lane]; }
    int kept_base = 0;
    __syncthreads();

    for (int tt = 0; tt < words; ++tt) {
      unsigned long long v[16];
      if (lane < words) {
        const unsigned long long* rowb =
            mask + ((size_t)tt * 64 + wv * 16) * words + lane;
#pragma unroll
        for (int s = 0; s < 16; ++s) v[s] = rowb[(size_t)s * words];
      }
      if (wv == 0) {
        unsigned long long wr = rem[tt];
        bool rm = (wr >> lane) & 1ull;
        bool kp = false;
        unsigned long long Rv = wr;
        unsigned long long Kv = 0ull;
        while (true) {
          bool F = (!rm) && (!kp) && ((colv & ~Rv) == 0ull);
          unsigned long long Fv = __ballot(F);
          if (Fv == 0ull) break;
          kp = kp || F;
          Kv |= Fv;
          bool newr = (!rm) && (!kp) && ((colv & Fv) != 0ull);
          rm = rm || newr;
          Rv = __ballot(rm);
        }
        if (kp) {
          int rank = kept_base + __popcll(Kv & ((1ull << lane) - 1ull));
          if (rank < 1000) { csb[rank] = sc_i; cbb[rank] = bx_i; }
        }
        kept_base += __popcll(Kv);
        if (lane == 0) {
          *keepShp = Kv;
          *doneShp = (kept_base >= 1000 || tt + 1 >= words) ? 1 : 0;
        }
        if (tt + 1 < words) {
          int i2 = (tt + 1) * 64 + lane;
          colv = colD[i2]; sc_i = ssc[i2]; bx_i = sbox[i2];
        }
      }
      __syncthreads();
      unsigned long long k64 = *keepShp;
      int done = *doneShp;
      if (lane < words) {
        unsigned long long acc = 0ull;
#pragma unroll
        for (int s = 0; s < 16; ++s)
          acc |= (((k64 >> (wv * 16 + s)) & 1ull) ? v[s] : 0ull);
        npart[wv][lane] = acc;
      }
      __syncthreads();
      if (done) break;
      if (t > tt && t < words)
        rem[t] |= npart[0][t] | npart[1][t] | npart[2][t] | npart[3][t];
      __syncthreads();
    }
  }
  soft_barrier(bar, 3);

  // ------ P4: final stable descending sort of 2000, gather boxes ------------
  if (blockIdx.x < 32) {
    float* s = (float*)smem;
    int b = blockIdx.x >> 3, c = blockIdx.x & 7;
    const float* csb = cs + (size_t)b * 2000;
    for (int j = t; j < 2000; j += 256) s[j] = csb[j];
    __syncthreads();
    if (t < 250) {
      int li = c * 250 + t;
      float si = s[li];
      int rank = 0;
      const float4* sv = (const float4*)s;
      for (int j4 = 0; j4 < 500; ++j4) {
        float4 v = sv[j4];
        int j = j4 * 4;
        rank += (v.x > si) || (v.x == si && (j + 0) < li);
        rank += (v.y > si) || (v.y == si && (j + 1) < li);
        rank += (v.z > si) || (v.z == si && (j + 2) < li);
        rank += (v.w > si) || (v.w == si && (j + 3) < li);
      }
      float4 bi = ((const float4*)cb)[(size_t)b * 2000 + li];
      ((float4*)out)[(size_t)b * 2000 + rank] = bi;
    }
  }
}

// ============================================================================
extern "C" void kernel_launch(void* const* d_in, const int* in_sizes, int n_in,
                              void* d_out, int out_size, void* d_ws, size_t ws_size,
                              hipStream_t stream) {
  const float* feat0  = (const float*)d_in[0];
  const float* feat1  = (const float*)d_in[1];
  const float* conv_w = (const float*)d_in[2];
  const float* conv_b = (const float*)d_in[3];
  const float* cls_w  = (const float*)d_in[4];
  const float* cls_b  = (const float*)d_in[5];
  const float* reg_w  = (const float*)d_in[6];
  const float* reg_b  = (const float*)d_in[7];

  char* p = (char*)d_ws;
  auto alloc = [&](size_t bytes) {
    char* r = p;
    p += (bytes + 255) & ~(size_t)255;
    return r;
  };
  double* part0 = (double*)alloc((size_t)4 * 4096 * 256 * 8);    // 33.6 MB
  double* part1 = (double*)alloc((size_t)4 * 1024 * 256 * 8);    //  8.4 MB
  float* box0 = (float*)alloc((size_t)4 * 3072 * 16);
  float* sc0  = (float*)alloc((size_t)4 * 3072 * 4);
  float* box1 = (float*)alloc((size_t)4 * 768 * 16);
  float* sc1  = (float*)alloc((size_t)4 * 768 * 4);
  float* sbox0 = (float*)alloc((size_t)4 * 3072 * 16);
  float* ssc0  = (float*)alloc((size_t)4 * 3072 * 4);
  float* sbox1 = (float*)alloc((size_t)4 * 768 * 16);
  float* ssc1  = (float*)alloc((size_t)4 * 768 * 4);
  unsigned long long* mask0 = (unsigned long long*)alloc((size_t)4 * 3072 * 48 * 8);
  unsigned long long* mask1 = (unsigned long long*)alloc((size_t)4 * 768 * 12 * 8);
  unsigned long long* colD0 = (unsigned long long*)alloc((size_t)4 * 3072 * 8);
  unsigned long long* colD1 = (unsigned long long*)alloc((size_t)4 * 768 * 8);
  float* cb = (float*)alloc((size_t)4 * 2000 * 16);
  float* cs = (float*)alloc((size_t)4 * 2000 * 4);
  unsigned int* bar = (unsigned int*)alloc(256);
  float* outp = (float*)d_out;

  hipMemsetAsync(bar, 0, 256, stream);   // zero barrier counters (per launch)
  conv3_sk_u<<<1280, 256, 0, stream>>>(feat0, feat1, conv_w, part0, part1);
  fused_post_k<<<512, 256, 0, stream>>>(
      part0, part1, conv_b, cls_w, cls_b, reg_w, reg_b,
      box0, sc0, box1, sc1, sbox0, ssc0, sbox1, ssc1,
      mask0, mask1, colD0, colD1, cb, cs, outp, bar);
}